// Round 5
// baseline (1418.236 us; speedup 1.0000x reference)
//
#include <hip/hip_runtime.h>
#include <hip/hip_bf16.h>

// 4 stacked LSTM layers (512->64, 64->64, 64->6, 6->6) + FC(6->6).
// B=64, T=1024, M = B*T = 65536.
//
// R10: mega-block. R9's pipe ran at 2196 cy/step because role 1 carried 2x
//      work (proj+recurrent) and role 2 serialized proj+cells on one wave.
//      The pipeline rate = slowest stage, so: give EVERY stage its own
//      wave(s), each with chain <= the R6-proven 1062-cy gate chain, all in
//      ONE block per batch (15 waves), handing off through double-buffered
//      LDS riding ONE barrier per step:
//        waves 0-3 : L1 gates (exact R6 step)        -> g1ls
//        wave 0 also publishes h1 packed-f16 pairs   -> h1pk (128B)
//        waves 4-7 : L2 input proj, lag 1 (LDS-bcast h1 pairs + 32 fdot2)
//                                                    -> prel2
//        waves 8-11: L2 recurrent gates (R6 step, a0 = prel2)  -> g2ls
//        wave 8 also publishes h2 f32                -> h2f
//        waves12-13: L3 proj, 2x32 dims f32          -> prl3
//        wave 14   : L3+L4+FC cells (scan66-unified lanes), writes out
//      Write@m -> barrier -> read@m+1; overwrite@m+2 is after barrier(m+1):
//      the proven one-barrier discipline. No flags, no co-residency
//      assumptions, no h1/h2/xg2 global round-trips. Loop T+8 steps.

#define B_SZ 64
#define T_SZ 1024
#define M_SZ (B_SZ * T_SZ)
#define NT (T_SZ + 8)

typedef _Float16 h2   __attribute__((ext_vector_type(2)));
typedef _Float16 h8   __attribute__((ext_vector_type(8)));
typedef float    f32x4 __attribute__((ext_vector_type(4)));
typedef unsigned u32x4 __attribute__((ext_vector_type(4)));

__device__ __forceinline__ float sigm_f(float x) {
    return 1.0f / (1.0f + __expf(-x));
}
__device__ __forceinline__ float tanh_f(float x) {
    return 2.0f / (1.0f + __expf(-2.0f * x)) - 1.0f;
}

__device__ __forceinline__ float fdot2f(h2 a, h2 b, float c) {
#if __has_builtin(__builtin_amdgcn_fdot2)
    return __builtin_amdgcn_fdot2(a, b, c, false);
#else
    return c + (float)a.x * (float)b.x + (float)a.y * (float)b.y;
#endif
}

__device__ __forceinline__ unsigned pack_h2(float a, float b) {
    h2 p; p.x = (_Float16)a; p.y = (_Float16)b;
    return __builtin_bit_cast(unsigned, p);
}
__device__ __forceinline__ h2 as_h2(unsigned x) { return __builtin_bit_cast(h2, x); }
__device__ __forceinline__ float as_f(unsigned x) { return __builtin_bit_cast(float, x); }
__device__ __forceinline__ float as_f(int x) { return __builtin_bit_cast(float, x); }

// even lane 2i ends with {h[2i], h[2i+1]} packed as 2xf16
__device__ __forceinline__ int pack_pair(float h) {
    const _Float16 hf = (_Float16)h;
    const int hb = (int)__builtin_bit_cast(unsigned short, hf);
    const int nb = __builtin_amdgcn_update_dpp(0, hb, 0xB1, 0xF, 0xF, true);
    return hb | (nb << 16);
}

__device__ __forceinline__ void lstm_cell(float p0, float p1, float p2, float p3,
                                          float& c, float& h) {
    const float iv = sigm_f(p0);
    const float fv = sigm_f(p1);
    const float gv = tanh_f(p2);
    const float ov = sigm_f(p3);
    c = fv * c + iv * gv;
    h = ov * tanh_f(c);
}

// ---------------- fp32 -> f16 converter (for W_ih weights) ------------------
__global__ __launch_bounds__(256) void f32_to_f16(const float* __restrict__ src,
                                                  _Float16* __restrict__ dst, int n) {
    const int i = blockIdx.x * 256 + threadIdx.x;
    if (i < n) dst[i] = (_Float16)src[i];
}

// ---------------- MFMA input-projection GEMM (layer 1 only) -----------------
template <int K>
__global__ __launch_bounds__(256) void gemm_mfma(const float* __restrict__ X,
                                                 const _Float16* __restrict__ W16,
                                                 const float* __restrict__ bias,
                                                 float* __restrict__ out) {
    const int m0   = blockIdx.x * 64;
    const int tid  = threadIdx.x;
    const int wv   = tid >> 6;
    const int lane = tid & 63;
    const int lh   = lane & 15;
    const int quad = lane >> 4;
    const int n0   = wv * 64;

    __shared__ __align__(16) _Float16 Als[64 * 32];

    f32x4 acc[4][4];
#pragma unroll
    for (int nt = 0; nt < 4; ++nt) {
        const float bg = bias[n0 + nt * 16 + lh];
#pragma unroll
        for (int mt = 0; mt < 4; ++mt) {
            acc[mt][nt].x = bg; acc[mt][nt].y = bg;
            acc[mt][nt].z = bg; acc[mt][nt].w = bg;
        }
    }

    const int srow = tid >> 2;
    const int sk8  = tid & 3;
    const int sdst = srow * 32 + ((sk8 ^ (srow & 3)) * 8);

    for (int k0 = 0; k0 < K; k0 += 32) {
        const float* xr = X + (size_t)(m0 + srow) * K + k0 + sk8 * 8;
        const float4 a4 = ((const float4*)xr)[0];
        const float4 b4 = ((const float4*)xr)[1];
        h8 bfrag[4];
#pragma unroll
        for (int nt = 0; nt < 4; ++nt) {
            bfrag[nt] = *(const h8*)&W16[(size_t)(n0 + nt * 16 + lh) * K + k0 + quad * 8];
        }
        h8 hv;
        hv[0] = (_Float16)a4.x; hv[1] = (_Float16)a4.y;
        hv[2] = (_Float16)a4.z; hv[3] = (_Float16)a4.w;
        hv[4] = (_Float16)b4.x; hv[5] = (_Float16)b4.y;
        hv[6] = (_Float16)b4.z; hv[7] = (_Float16)b4.w;

        __syncthreads();
        *(h8*)&Als[sdst] = hv;
        __syncthreads();

        h8 afrag[4];
#pragma unroll
        for (int mt = 0; mt < 4; ++mt) {
            const int row = mt * 16 + lh;
            afrag[mt] = *(const h8*)&Als[row * 32 + ((quad ^ (row & 3)) * 8)];
        }
#pragma unroll
        for (int mt = 0; mt < 4; ++mt)
#pragma unroll
            for (int nt = 0; nt < 4; ++nt)
                acc[mt][nt] = __builtin_amdgcn_mfma_f32_16x16x32_f16(
                    afrag[mt], bfrag[nt], acc[mt][nt], 0, 0, 0);
    }

#pragma unroll
    for (int mt = 0; mt < 4; ++mt)
#pragma unroll
        for (int nt = 0; nt < 4; ++nt)
#pragma unroll
            for (int r = 0; r < 4; ++r)
                out[(size_t)(m0 + mt * 16 + quad * 4 + r) * 256 + n0 + nt * 16 + lh] =
                    acc[mt][nt][r];
}

// ---------------- mega-block: all recurrent layers, one block per batch -----
__global__ __launch_bounds__(960) void lstm_mega(
        const float* __restrict__ xg1,    // [B,T,256]  (b1_0 folded)
        const float* __restrict__ whh1,   // [256][64]
        const float* __restrict__ wih2,   // [256][64]
        const float* __restrict__ whh2,   // [256][64]
        const float* __restrict__ b2v,    // [256]
        const float* __restrict__ wih3,   // [24][64]
        const float* __restrict__ whh3,   // [24][6]
        const float* __restrict__ b3v,    // [24]
        const float* __restrict__ wih4,   // [24][6]
        const float* __restrict__ whh4,   // [24][6]
        const float* __restrict__ b4v,    // [24]
        const float* __restrict__ fcw,    // [6][6]
        const float* __restrict__ fcb,    // [6]
        float* __restrict__ out) {        // [B,T,6]
    const int b   = blockIdx.x;
    const int tid = threadIdx.x;
    const int wid = tid >> 6;
    const int u   = tid & 63;

    __shared__ __align__(16) float    g1ls[2][4][64];   // L1 gate pre-acts
    __shared__ __align__(16) float    prel2[2][4][64];  // L2 input-proj
    __shared__ __align__(16) float    g2ls[2][4][64];   // L2 gate pre-acts
    __shared__ __align__(16) unsigned h1pk[2][32];      // h1 packed f16 pairs
    __shared__ __align__(16) float    h2f[2][64];       // h2 f32
    __shared__ __align__(16) float    prl3[2][2][32];   // L3 proj partials

    unsigned wreg[48];
#pragma unroll
    for (int i = 0; i < 48; ++i) wreg[i] = 0u;
    float wf[8] = {0.f, 0.f, 0.f, 0.f, 0.f, 0.f, 0.f, 0.f};
    float wb[4] = {0.f, 0.f, 0.f, 0.f};
    float xv[4] = {0.f, 0.f, 0.f, 0.f};
    float breg = 0.0f;
    float hS = 0.0f, cS = 0.0f;
    int pk = 0;

    const float* xgb = xg1 + (size_t)b * T_SZ * 256 + (wid & 3) * 64 + u;

    if (wid < 4) {                       // L1 gate wave g=wid
        const float* wrow = whh1 + (size_t)(wid * 64 + u) * 64;
#pragma unroll
        for (int k2 = 0; k2 < 32; ++k2) wreg[k2] = pack_h2(wrow[2 * k2], wrow[2 * k2 + 1]);
#pragma unroll
        for (int s = 0; s < 4; ++s) xv[s] = xgb[(size_t)s * 256];
    } else if (wid < 8) {                // L2 input-proj wave pg=wid-4
        const float* wrow = wih2 + (size_t)((wid - 4) * 64 + u) * 64;
#pragma unroll
        for (int k2 = 0; k2 < 32; ++k2) wreg[k2] = pack_h2(wrow[2 * k2], wrow[2 * k2 + 1]);
        breg = b2v[(wid - 4) * 64 + u];
    } else if (wid < 12) {               // L2 recurrent wave rg=wid-8
        const float* wrow = whh2 + (size_t)((wid - 8) * 64 + u) * 64;
#pragma unroll
        for (int k2 = 0; k2 < 32; ++k2) wreg[k2] = pack_h2(wrow[2 * k2], wrow[2 * k2 + 1]);
    } else if (wid < 14) {               // L3 proj wave j=wid-12 (dims 32j..32j+32)
        if (u < 24) {
            const int j = wid - 12;
#pragma unroll
            for (int k = 0; k < 32; ++k)
                wreg[k] = __builtin_bit_cast(unsigned, wih3[(size_t)u * 64 + 32 * j + k]);
            breg = (j == 0) ? b3v[u] : 0.0f;
        }
    } else {                             // cells wave
        if (u < 6) {
#pragma unroll
            for (int g4 = 0; g4 < 4; ++g4)
#pragma unroll
                for (int k = 0; k < 6; ++k)
                    wreg[g4 * 12 + k] = __builtin_bit_cast(unsigned, whh3[(g4 * 6 + u) * 6 + k]);
        } else if (u < 12) {
            const int q = u - 6;
#pragma unroll
            for (int g4 = 0; g4 < 4; ++g4) {
#pragma unroll
                for (int k = 0; k < 6; ++k) {
                    wreg[g4 * 12 + k]     = __builtin_bit_cast(unsigned, wih4[(g4 * 6 + q) * 6 + k]);
                    wreg[g4 * 12 + 6 + k] = __builtin_bit_cast(unsigned, whh4[(g4 * 6 + q) * 6 + k]);
                }
                wb[g4] = b4v[g4 * 6 + q];
            }
        } else if (u < 18) {
            const int q = u - 12;
#pragma unroll
            for (int k = 0; k < 6; ++k) wf[k] = fcw[q * 6 + k];
            wf[6] = fcb[q];
        }
    }

    float* outb = out + (size_t)b * T_SZ * 6;

    for (int m4 = 0; m4 < NT; m4 += 4) {
#pragma unroll
        for (int s = 0; s < 4; ++s) {
            const int m   = m4 + s;
            const int cur = s & 1;
            const int prv = cur ^ 1;

            // ======================= pre-barrier phase =======================
            if (wid < 4) {
                // publish h1[m-1] pairs (wave 0, even lanes)
                if (wid == 0 && m >= 1 && m <= T_SZ && !(u & 1))
                    h1pk[cur][u >> 1] = (unsigned)pk;
                if (m < T_SZ) {
                    float a0 = xv[s], a1 = 0.f, a2 = 0.f, a3 = 0.f;
#pragma unroll
                    for (int k8 = 0; k8 < 8; ++k8) {
                        const int hs0 = __builtin_amdgcn_readlane(pk, 8 * k8 + 0);
                        const int hs1 = __builtin_amdgcn_readlane(pk, 8 * k8 + 2);
                        const int hs2 = __builtin_amdgcn_readlane(pk, 8 * k8 + 4);
                        const int hs3 = __builtin_amdgcn_readlane(pk, 8 * k8 + 6);
                        a0 = fdot2f(as_h2(wreg[4 * k8 + 0]), __builtin_bit_cast(h2, hs0), a0);
                        a1 = fdot2f(as_h2(wreg[4 * k8 + 1]), __builtin_bit_cast(h2, hs1), a1);
                        a2 = fdot2f(as_h2(wreg[4 * k8 + 2]), __builtin_bit_cast(h2, hs2), a2);
                        a3 = fdot2f(as_h2(wreg[4 * k8 + 3]), __builtin_bit_cast(h2, hs3), a3);
                    }
                    g1ls[cur][wid][u] = (a0 + a1) + (a2 + a3);
                }
            } else if (wid < 8) {
                // xg2[m-2] = b2 + wih2 . h1[m-2]  (h1 pairs via LDS broadcast)
                if (m >= 2 && m < T_SZ + 2) {
                    const u32x4* hp = (const u32x4*)&h1pk[prv][0];
                    float a0 = breg, a1 = 0.f, a2 = 0.f, a3 = 0.f;
#pragma unroll
                    for (int r = 0; r < 8; ++r) {
                        const u32x4 q = hp[r];
                        a0 = fdot2f(as_h2(wreg[4 * r + 0]), as_h2(q[0]), a0);
                        a1 = fdot2f(as_h2(wreg[4 * r + 1]), as_h2(q[1]), a1);
                        a2 = fdot2f(as_h2(wreg[4 * r + 2]), as_h2(q[2]), a2);
                        a3 = fdot2f(as_h2(wreg[4 * r + 3]), as_h2(q[3]), a3);
                    }
                    prel2[cur][wid - 4][u] = (a0 + a1) + (a2 + a3);
                }
            } else if (wid < 12) {
                // publish h2[m-4] f32 (wave 8)
                if (wid == 8 && m >= 4 && m <= T_SZ + 3) h2f[cur][u] = hS;
                // L2 gates for t2 = m-3: a0 = prel2 (bias folded) + whh2 . h2[t2-1]
                if (m >= 3 && m < T_SZ + 3) {
                    float a0 = prel2[prv][wid - 8][u], a1 = 0.f, a2 = 0.f, a3 = 0.f;
#pragma unroll
                    for (int k8 = 0; k8 < 8; ++k8) {
                        const int hs0 = __builtin_amdgcn_readlane(pk, 8 * k8 + 0);
                        const int hs1 = __builtin_amdgcn_readlane(pk, 8 * k8 + 2);
                        const int hs2 = __builtin_amdgcn_readlane(pk, 8 * k8 + 4);
                        const int hs3 = __builtin_amdgcn_readlane(pk, 8 * k8 + 6);
                        a0 = fdot2f(as_h2(wreg[4 * k8 + 0]), __builtin_bit_cast(h2, hs0), a0);
                        a1 = fdot2f(as_h2(wreg[4 * k8 + 1]), __builtin_bit_cast(h2, hs1), a1);
                        a2 = fdot2f(as_h2(wreg[4 * k8 + 2]), __builtin_bit_cast(h2, hs2), a2);
                        a3 = fdot2f(as_h2(wreg[4 * k8 + 3]), __builtin_bit_cast(h2, hs3), a3);
                    }
                    g2ls[cur][wid - 8][u] = (a0 + a1) + (a2 + a3);
                }
            } else if (wid < 14) {
                // L3 proj half j for t3 = m-5 over h2f[prv]
                if (m >= 5 && m < T_SZ + 5) {
                    const f32x4* hv4 = (const f32x4*)&h2f[prv][32 * (wid - 12)];
                    float d0 = breg, d1 = 0.f, d2 = 0.f, d3 = 0.f;
#pragma unroll
                    for (int r = 0; r < 8; ++r) {
                        const f32x4 q = hv4[r];
                        d0 = fmaf(as_f(wreg[4 * r + 0]), q[0], d0);
                        d1 = fmaf(as_f(wreg[4 * r + 1]), q[1], d1);
                        d2 = fmaf(as_f(wreg[4 * r + 2]), q[2], d2);
                        d3 = fmaf(as_f(wreg[4 * r + 3]), q[3], d3);
                    }
                    if (u < 24) prl3[cur][wid - 12][u] = (d0 + d1) + (d2 + d3);
                }
            } else {
                // cells: t = m-6. v3 = h3[t-1] (lanes 0-5), v4 = h4[t-2] (6-11)
                const int t = m - 6;
                const int hb = __builtin_bit_cast(int, hS);
                float v[12];
#pragma unroll
                for (int k = 0; k < 12; ++k)
                    v[k] = as_f(__builtin_amdgcn_readlane(hb, k));
                // FC: out[t-2] from h4[t-2]
                if (m >= 8 && m < T_SZ + 8 && u >= 12 && u < 18) {
                    float o = wf[6];
#pragma unroll
                    for (int k = 0; k < 6; ++k) o = fmaf(wf[k], v[6 + k], o);
                    outb[(size_t)(m - 8) * 6 + (u - 12)] = o;
                }
                if (m >= 6 && m < T_SZ + 7) {
                    float pj[4] = {0.f, 0.f, 0.f, 0.f};
                    if (m < T_SZ + 6) {
#pragma unroll
                        for (int g4 = 0; g4 < 4; ++g4) {
                            const int r = g4 * 6 + (u % 6);
                            pj[g4] = prl3[prv][0][r] + prl3[prv][1][r];
                        }
                    }
                    const bool is_l4 = (u >= 6 && u < 12);
                    float pg[4];
#pragma unroll
                    for (int g4 = 0; g4 < 4; ++g4) {
                        float a = is_l4 ? wb[g4] : pj[g4];
#pragma unroll
                        for (int k = 0; k < 12; ++k)
                            a = fmaf(as_f(wreg[g4 * 12 + k]), v[k], a);
                        pg[g4] = a;
                    }
                    const bool act = (u < 6 && t < T_SZ) || (is_l4 && t >= 1 && t <= T_SZ);
                    if (act) lstm_cell(pg[0], pg[1], pg[2], pg[3], cS, hS);
                }
            }

            asm volatile("s_waitcnt lgkmcnt(0)" ::: "memory");
            __builtin_amdgcn_s_barrier();
            asm volatile("" ::: "memory");

            // ======================= post-barrier phase ======================
            if (wid < 4) {
                if (m < T_SZ) {
                    const float p0 = g1ls[cur][0][u];
                    const float p1 = g1ls[cur][1][u];
                    const float p2 = g1ls[cur][2][u];
                    const float p3 = g1ls[cur][3][u];
                    const int tp = (m + 4 < T_SZ) ? (m + 4) : (T_SZ - 1);
                    xv[s] = xgb[(size_t)tp * 256];
                    lstm_cell(p0, p1, p2, p3, cS, hS);
                    pk = pack_pair(hS);
                }
            } else if (wid >= 8 && wid < 12) {
                if (m >= 3 && m < T_SZ + 3) {
                    const float p0 = g2ls[cur][0][u];
                    const float p1 = g2ls[cur][1][u];
                    const float p2 = g2ls[cur][2][u];
                    const float p3 = g2ls[cur][3][u];
                    lstm_cell(p0, p1, p2, p3, cS, hS);
                    pk = pack_pair(hS);
                }
            }
        }
    }
}

extern "C" void kernel_launch(void* const* d_in, const int* in_sizes, int n_in,
                              void* d_out, int out_size, void* d_ws, size_t ws_size,
                              hipStream_t stream) {
    const float* x      = (const float*)d_in[0];
    const float* w1_ih0 = (const float*)d_in[1];
    const float* w1_hh0 = (const float*)d_in[2];
    const float* b1_0   = (const float*)d_in[3];
    const float* w1_ih1 = (const float*)d_in[4];
    const float* w1_hh1 = (const float*)d_in[5];
    const float* b1_1   = (const float*)d_in[6];
    const float* w2_ih0 = (const float*)d_in[7];
    const float* w2_hh0 = (const float*)d_in[8];
    const float* b2_0   = (const float*)d_in[9];
    const float* w2_ih1 = (const float*)d_in[10];
    const float* w2_hh1 = (const float*)d_in[11];
    const float* b2_1   = (const float*)d_in[12];
    const float* fc_w   = (const float*)d_in[13];
    const float* fc_b   = (const float*)d_in[14];
    float* out = (float*)d_out;

    const int M = M_SZ;
    float*    xg   = (float*)d_ws;                      // M*256 f32
    _Float16* w16a = (_Float16*)(xg + (size_t)M * 256); // 256*512 f16

    f32_to_f16<<<(256 * 512 + 255) / 256, 256, 0, stream>>>(w1_ih0, w16a, 256 * 512);

    // L1 input projection (x known upfront): 512 -> 256 gates, bias folded
    gemm_mfma<512><<<M / 64, 256, 0, stream>>>(x, w16a, b1_0, xg);

    // all recurrent layers in one 15-wave block per batch
    lstm_mega<<<B_SZ, 960, 0, stream>>>(xg, w1_hh0,
                                        w1_ih1, w1_hh1, b1_1,
                                        w2_ih0, w2_hh0, b2_0,
                                        w2_ih1, w2_hh1, b2_1,
                                        fc_w, fc_b, out);
}

// Round 6
// 1343.556 us; speedup vs baseline: 1.0556x; 1.0556x over previous
//
#include <hip/hip_runtime.h>
#include <hip/hip_bf16.h>

// 4 stacked LSTM layers (512->64, 64->64, 64->6, 6->6) + FC(6->6).
// B=64, T=1024, M = B*T = 65536.
//
// R11: balanced cross-block pipeline. R9 (pipe, 937us) was rate-limited by
//      role 1's double chain (proj+recurrent ~2196 cy/step); R10 (mega-block)
//      showed stacking stages on one CU sums their issue (~2790 cy/step).
//      Fix: keep stages on separate CUs (R9 topology) and move ALL
//      non-recurrent work into chunked throughput roles:
//        role 0 (blocks   0- 63, 4 waves): L1 scan (R6 step) -> h1p, flag0
//        role 1 (blocks  64-127, 4 waves): pre2 = b2 + wih2.h1, chunk-GEMM,
//                writes IN-PLACE over consumed xg rows, flag1
//        role 2 (blocks 128-191, 4 waves): L2 recurrent scan, EXACT R6 shape
//                (a0 = prefetched pre2, 32 fdot2) -> h2g, flag2
//        role 3 (blocks 192-255, 1 wave): proj3 = b3 + wih3.h2 chunk-GEMM
//                -> pr3, flag3
//        role 4 (blocks 256-319, 1 wave): L3+L4+FC cells only (short chain)
//      bid = role*64 + b  =>  XCD = b&7 for every role: each batch's whole
//      pipeline shares one XCD's L2 for flag/data traffic. All 320 blocks
//      co-resident (256 thr, ~100 VGPR, 2KB LDS). Chunked flags (CHUNK=16,
//      PF=4) as proven in R9.

#define B_SZ 64
#define T_SZ 1024
#define M_SZ (B_SZ * T_SZ)
#define CHUNK 16
#define PF 4

typedef _Float16 h2   __attribute__((ext_vector_type(2)));
typedef _Float16 h8   __attribute__((ext_vector_type(8)));
typedef float    f32x4 __attribute__((ext_vector_type(4)));

__device__ __forceinline__ float sigm_f(float x) {
    return 1.0f / (1.0f + __expf(-x));
}
__device__ __forceinline__ float tanh_f(float x) {
    return 2.0f / (1.0f + __expf(-2.0f * x)) - 1.0f;
}

__device__ __forceinline__ float fdot2f(h2 a, h2 b, float c) {
#if __has_builtin(__builtin_amdgcn_fdot2)
    return __builtin_amdgcn_fdot2(a, b, c, false);
#else
    return c + (float)a.x * (float)b.x + (float)a.y * (float)b.y;
#endif
}

__device__ __forceinline__ unsigned pack_h2(float a, float b) {
    h2 p; p.x = (_Float16)a; p.y = (_Float16)b;
    return __builtin_bit_cast(unsigned, p);
}
__device__ __forceinline__ h2 as_h2(unsigned x) { return __builtin_bit_cast(h2, x); }
__device__ __forceinline__ float as_f(unsigned x) { return __builtin_bit_cast(float, x); }
__device__ __forceinline__ float as_f(int x) { return __builtin_bit_cast(float, x); }

// even lane 2i ends with {h[2i], h[2i+1]} packed as 2xf16
__device__ __forceinline__ int pack_pair(float h) {
    const _Float16 hf = (_Float16)h;
    const int hb = (int)__builtin_bit_cast(unsigned short, hf);
    const int nb = __builtin_amdgcn_update_dpp(0, hb, 0xB1, 0xF, 0xF, true);
    return hb | (nb << 16);
}

__device__ __forceinline__ void lstm_cell(float p0, float p1, float p2, float p3,
                                          float& c, float& h) {
    const float iv = sigm_f(p0);
    const float fv = sigm_f(p1);
    const float gv = tanh_f(p2);
    const float ov = sigm_f(p3);
    c = fv * c + iv * gv;
    h = ov * tanh_f(c);
}

__device__ __forceinline__ void wait_flag(const unsigned* f, unsigned need) {
    while (__hip_atomic_load(f, __ATOMIC_RELAXED, __HIP_MEMORY_SCOPE_AGENT) < need)
        __builtin_amdgcn_s_sleep(2);
    (void)__hip_atomic_load(f, __ATOMIC_ACQUIRE, __HIP_MEMORY_SCOPE_AGENT);
}
__device__ __forceinline__ void publish_flag(unsigned* f, unsigned v) {
    __hip_atomic_store(f, v, __ATOMIC_RELEASE, __HIP_MEMORY_SCOPE_AGENT);
}

// ---------------- fp32 -> f16 converter (for W_ih weights) ------------------
__global__ __launch_bounds__(256) void f32_to_f16(const float* __restrict__ src,
                                                  _Float16* __restrict__ dst, int n) {
    const int i = blockIdx.x * 256 + threadIdx.x;
    if (i < n) dst[i] = (_Float16)src[i];
}

__global__ void init_flags(unsigned* f) { f[threadIdx.x] = 0; }

// ---------------- MFMA input-projection GEMM (layer 1 only) -----------------
template <int K>
__global__ __launch_bounds__(256) void gemm_mfma(const float* __restrict__ X,
                                                 const _Float16* __restrict__ W16,
                                                 const float* __restrict__ bias,
                                                 float* __restrict__ out) {
    const int m0   = blockIdx.x * 64;
    const int tid  = threadIdx.x;
    const int wv   = tid >> 6;
    const int lane = tid & 63;
    const int lh   = lane & 15;
    const int quad = lane >> 4;
    const int n0   = wv * 64;

    __shared__ __align__(16) _Float16 Als[64 * 32];

    f32x4 acc[4][4];
#pragma unroll
    for (int nt = 0; nt < 4; ++nt) {
        const float bg = bias[n0 + nt * 16 + lh];
#pragma unroll
        for (int mt = 0; mt < 4; ++mt) {
            acc[mt][nt].x = bg; acc[mt][nt].y = bg;
            acc[mt][nt].z = bg; acc[mt][nt].w = bg;
        }
    }

    const int srow = tid >> 2;
    const int sk8  = tid & 3;
    const int sdst = srow * 32 + ((sk8 ^ (srow & 3)) * 8);

    for (int k0 = 0; k0 < K; k0 += 32) {
        const float* xr = X + (size_t)(m0 + srow) * K + k0 + sk8 * 8;
        const float4 a4 = ((const float4*)xr)[0];
        const float4 b4 = ((const float4*)xr)[1];
        h8 bfrag[4];
#pragma unroll
        for (int nt = 0; nt < 4; ++nt) {
            bfrag[nt] = *(const h8*)&W16[(size_t)(n0 + nt * 16 + lh) * K + k0 + quad * 8];
        }
        h8 hv;
        hv[0] = (_Float16)a4.x; hv[1] = (_Float16)a4.y;
        hv[2] = (_Float16)a4.z; hv[3] = (_Float16)a4.w;
        hv[4] = (_Float16)b4.x; hv[5] = (_Float16)b4.y;
        hv[6] = (_Float16)b4.z; hv[7] = (_Float16)b4.w;

        __syncthreads();
        *(h8*)&Als[sdst] = hv;
        __syncthreads();

        h8 afrag[4];
#pragma unroll
        for (int mt = 0; mt < 4; ++mt) {
            const int row = mt * 16 + lh;
            afrag[mt] = *(const h8*)&Als[row * 32 + ((quad ^ (row & 3)) * 8)];
        }
#pragma unroll
        for (int mt = 0; mt < 4; ++mt)
#pragma unroll
            for (int nt = 0; nt < 4; ++nt)
                acc[mt][nt] = __builtin_amdgcn_mfma_f32_16x16x32_f16(
                    afrag[mt], bfrag[nt], acc[mt][nt], 0, 0, 0);
    }

#pragma unroll
    for (int mt = 0; mt < 4; ++mt)
#pragma unroll
        for (int nt = 0; nt < 4; ++nt)
#pragma unroll
            for (int r = 0; r < 4; ++r)
                out[(size_t)(m0 + mt * 16 + quad * 4 + r) * 256 + n0 + nt * 16 + lh] =
                    acc[mt][nt][r];
}

// ---------------- balanced pipelined scan, one role per block ---------------
__global__ __launch_bounds__(256, 1) void lstm_pipe(
        const float* __restrict__ xgc,    // [B,T,256] L1 gates; rows become pre2
        float* __restrict__ xgw,          // same buffer, writable alias
        const float* __restrict__ whh1,   // [256][64]
        const float* __restrict__ wih2,   // [256][64]
        const float* __restrict__ whh2,   // [256][64]
        const float* __restrict__ b2v,    // [256]
        const float* __restrict__ wih3,   // [24][64]
        const float* __restrict__ whh3,   // [24][6]
        const float* __restrict__ b3v,    // [24]
        const float* __restrict__ wih4,   // [24][6]
        const float* __restrict__ whh4,   // [24][6]
        const float* __restrict__ b4v,    // [24]
        const float* __restrict__ fcw,    // [6][6]
        const float* __restrict__ fcb,    // [6]
        unsigned* __restrict__ h1p,       // [B,T,32] packed f16 pairs of h1
        float* __restrict__ h2g,          // [B,T,64] f32 h2
        float* __restrict__ pr3,          // [B,T,24] f32 proj3
        unsigned* __restrict__ flags,     // 4 stages x 64 batches
        float* __restrict__ out) {        // [B,T,6]
    const int role = blockIdx.x >> 6;
    const int b    = blockIdx.x & 63;
    const int tid  = threadIdx.x;
    const int g    = tid >> 6;
    const int u    = tid & 63;

    __shared__ __align__(16) float pls[2][4][64];

    if (role == 0) {
        // =================== L1: proven R6 scan step ========================
        unsigned w[32];
        {
            const float* wr = whh1 + (size_t)(g * 64 + u) * 64;
#pragma unroll
            for (int k2 = 0; k2 < 32; ++k2) w[k2] = pack_h2(wr[2 * k2], wr[2 * k2 + 1]);
        }
        const float* xgb = xgc + (size_t)b * T_SZ * 256 + g * 64 + u;
        float xv[4];
#pragma unroll
        for (int s = 0; s < 4; ++s) xv[s] = xgb[(size_t)s * 256];
        unsigned* hp = h1p + (size_t)b * T_SZ * 32;
        unsigned* fl = flags + b;
        float c = 0.0f, h = 0.0f;
        int pkS = 0;

        for (int t4 = 0; t4 < T_SZ; t4 += 4) {
#pragma unroll
            for (int s = 0; s < 4; ++s) {
                const int t = t4 + s;
                float a0 = xv[s], a1 = 0.f, a2 = 0.f, a3 = 0.f;
#pragma unroll
                for (int k8 = 0; k8 < 8; ++k8) {
                    const int hs0 = __builtin_amdgcn_readlane(pkS, 8 * k8 + 0);
                    const int hs1 = __builtin_amdgcn_readlane(pkS, 8 * k8 + 2);
                    const int hs2 = __builtin_amdgcn_readlane(pkS, 8 * k8 + 4);
                    const int hs3 = __builtin_amdgcn_readlane(pkS, 8 * k8 + 6);
                    a0 = fdot2f(as_h2(w[4 * k8 + 0]), __builtin_bit_cast(h2, hs0), a0);
                    a1 = fdot2f(as_h2(w[4 * k8 + 1]), __builtin_bit_cast(h2, hs1), a1);
                    a2 = fdot2f(as_h2(w[4 * k8 + 2]), __builtin_bit_cast(h2, hs2), a2);
                    a3 = fdot2f(as_h2(w[4 * k8 + 3]), __builtin_bit_cast(h2, hs3), a3);
                }
                pls[t & 1][g][u] = (a0 + a1) + (a2 + a3);
                asm volatile("s_waitcnt lgkmcnt(0)" ::: "memory");
                __builtin_amdgcn_s_barrier();
                asm volatile("" ::: "memory");
                const float p0 = pls[t & 1][0][u];
                const float p1 = pls[t & 1][1][u];
                const float p2 = pls[t & 1][2][u];
                const float p3 = pls[t & 1][3][u];
                const int tp = (t + 4 < T_SZ) ? (t + 4) : (T_SZ - 1);
                xv[s] = xgb[(size_t)tp * 256];
                lstm_cell(p0, p1, p2, p3, c, h);
                pkS = pack_pair(h);
                if (g == 0) {
                    if (!(u & 1)) hp[(size_t)t * 32 + (u >> 1)] = (unsigned)pkS;
                    if (u == 0 && ((t & (CHUNK - 1)) == (CHUNK - 1)))
                        publish_flag(fl, (unsigned)(t + 1));
                }
            }
        }
    } else if (role == 1) {
        // ========= pre2 chunk-GEMM: xg2 = b2 + wih2 . h1  (in-place) =========
        unsigned wi[32];
        {
            const float* a = wih2 + (size_t)(g * 64 + u) * 64;
#pragma unroll
            for (int k2 = 0; k2 < 32; ++k2) wi[k2] = pack_h2(a[2 * k2], a[2 * k2 + 1]);
        }
        const float breg = b2v[g * 64 + u];
        const unsigned* hp = h1p + (size_t)b * T_SZ * 32;
        float* p2 = xgw + (size_t)b * T_SZ * 256 + g * 64 + u;
        unsigned* fin  = flags + b;
        unsigned* fout = flags + 64 + b;

        for (int c0 = 0; c0 < T_SZ; c0 += CHUNK) {
            wait_flag(fin, (unsigned)(c0 + CHUNK));
            for (int tt = c0; tt < c0 + CHUNK; tt += 4) {
                unsigned hv[4];
#pragma unroll
                for (int s = 0; s < 4; ++s) hv[s] = hp[(size_t)(tt + s) * 32 + (u & 31)];
#pragma unroll
                for (int s = 0; s < 4; ++s) {
                    const int hw = (int)hv[s];
                    float a0 = breg, a1 = 0.f, a2 = 0.f, a3 = 0.f;
#pragma unroll
                    for (int k8 = 0; k8 < 8; ++k8) {
                        const int j = 4 * k8;
                        const int i0 = __builtin_amdgcn_readlane(hw, j + 0);
                        const int i1 = __builtin_amdgcn_readlane(hw, j + 1);
                        const int i2 = __builtin_amdgcn_readlane(hw, j + 2);
                        const int i3 = __builtin_amdgcn_readlane(hw, j + 3);
                        a0 = fdot2f(as_h2(wi[j + 0]), __builtin_bit_cast(h2, i0), a0);
                        a1 = fdot2f(as_h2(wi[j + 1]), __builtin_bit_cast(h2, i1), a1);
                        a2 = fdot2f(as_h2(wi[j + 2]), __builtin_bit_cast(h2, i2), a2);
                        a3 = fdot2f(as_h2(wi[j + 3]), __builtin_bit_cast(h2, i3), a3);
                    }
                    p2[(size_t)(tt + s) * 256] = (a0 + a1) + (a2 + a3);
                }
            }
            publish_flag(fout, (unsigned)(c0 + CHUNK));
        }
    } else if (role == 2) {
        // ====== L2 recurrent scan: EXACT R6 shape, a0 = prefetched pre2 ======
        unsigned wh[32];
        {
            const float* a = whh2 + (size_t)(g * 64 + u) * 64;
#pragma unroll
            for (int k2 = 0; k2 < 32; ++k2) wh[k2] = pack_h2(a[2 * k2], a[2 * k2 + 1]);
        }
        const float* p2 = xgc + (size_t)b * T_SZ * 256 + g * 64 + u;
        float* h2b = h2g + (size_t)b * T_SZ * 64;
        unsigned* fin  = flags + 64 + b;
        unsigned* fout = flags + 128 + b;

        wait_flag(fin, (T_SZ < CHUNK + PF) ? T_SZ : (CHUNK + PF));
        float xv[4];
#pragma unroll
        for (int s = 0; s < 4; ++s) xv[s] = p2[(size_t)s * 256];
        float c = 0.0f, h = 0.0f;
        int pkQ = 0;

        for (int t4 = 0; t4 < T_SZ; t4 += 4) {
            if (t4 && (t4 & (CHUNK - 1)) == 0) {
                unsigned need = t4 + CHUNK + PF;
                if (need > T_SZ) need = T_SZ;
                wait_flag(fin, need);
            }
#pragma unroll
            for (int s = 0; s < 4; ++s) {
                const int t = t4 + s;
                float a0 = xv[s], a1 = 0.f, a2 = 0.f, a3 = 0.f;
#pragma unroll
                for (int k8 = 0; k8 < 8; ++k8) {
                    const int q0 = __builtin_amdgcn_readlane(pkQ, 8 * k8 + 0);
                    const int q1 = __builtin_amdgcn_readlane(pkQ, 8 * k8 + 2);
                    const int q2 = __builtin_amdgcn_readlane(pkQ, 8 * k8 + 4);
                    const int q3 = __builtin_amdgcn_readlane(pkQ, 8 * k8 + 6);
                    a0 = fdot2f(as_h2(wh[4 * k8 + 0]), __builtin_bit_cast(h2, q0), a0);
                    a1 = fdot2f(as_h2(wh[4 * k8 + 1]), __builtin_bit_cast(h2, q1), a1);
                    a2 = fdot2f(as_h2(wh[4 * k8 + 2]), __builtin_bit_cast(h2, q2), a2);
                    a3 = fdot2f(as_h2(wh[4 * k8 + 3]), __builtin_bit_cast(h2, q3), a3);
                }
                pls[t & 1][g][u] = (a0 + a1) + (a2 + a3);
                asm volatile("s_waitcnt lgkmcnt(0)" ::: "memory");
                __builtin_amdgcn_s_barrier();
                asm volatile("" ::: "memory");
                const float p0 = pls[t & 1][0][u];
                const float p1 = pls[t & 1][1][u];
                const float p2v = pls[t & 1][2][u];
                const float p3 = pls[t & 1][3][u];
                const int tp = (t + 4 < T_SZ) ? (t + 4) : (T_SZ - 1);
                xv[s] = p2[(size_t)tp * 256];
                lstm_cell(p0, p1, p2v, p3, c, h);
                pkQ = pack_pair(h);
                if (g == 0) {
                    h2b[(size_t)t * 64 + u] = h;
                    if (u == 0 && ((t & (CHUNK - 1)) == (CHUNK - 1)))
                        publish_flag(fout, (unsigned)(t + 1));
                }
            }
        }
    } else if (role == 3) {
        // ======== proj3 chunk-GEMM: pr3 = b3 + wih3 . h2  (one wave) =========
        if (tid >= 64) return;
        float pw[64];
#pragma unroll
        for (int j = 0; j < 64; ++j) pw[j] = 0.0f;
        float breg = 0.0f;
        if (u < 24) {
#pragma unroll
            for (int j = 0; j < 64; ++j) pw[j] = wih3[(size_t)u * 64 + j];
            breg = b3v[u];
        }
        const float* h2b = h2g + (size_t)b * T_SZ * 64;
        float* prb = pr3 + (size_t)b * T_SZ * 24;
        unsigned* fin  = flags + 128 + b;
        unsigned* fout = flags + 192 + b;

        for (int c0 = 0; c0 < T_SZ; c0 += CHUNK) {
            wait_flag(fin, (unsigned)(c0 + CHUNK));
            for (int tt = c0; tt < c0 + CHUNK; tt += 4) {
                float hv[4];
#pragma unroll
                for (int s = 0; s < 4; ++s) hv[s] = h2b[(size_t)(tt + s) * 64 + u];
#pragma unroll
                for (int s = 0; s < 4; ++s) {
                    const int hw = __builtin_bit_cast(int, hv[s]);
                    float d0 = breg, d1 = 0.f, d2 = 0.f, d3 = 0.f;
#pragma unroll
                    for (int j = 0; j < 64; j += 4) {
                        d0 = fmaf(pw[j + 0], as_f(__builtin_amdgcn_readlane(hw, j + 0)), d0);
                        d1 = fmaf(pw[j + 1], as_f(__builtin_amdgcn_readlane(hw, j + 1)), d1);
                        d2 = fmaf(pw[j + 2], as_f(__builtin_amdgcn_readlane(hw, j + 2)), d2);
                        d3 = fmaf(pw[j + 3], as_f(__builtin_amdgcn_readlane(hw, j + 3)), d3);
                    }
                    if (u < 24) prb[(size_t)(tt + s) * 24 + u] = (d0 + d1) + (d2 + d3);
                }
            }
            publish_flag(fout, (unsigned)(c0 + CHUNK));
        }
    } else {
        // ============ cells only: L3 + L4 + FC, one wave, short chain ========
        if (tid >= 64) return;
        float pw[48];
#pragma unroll
        for (int j = 0; j < 48; ++j) pw[j] = 0.0f;
        float wf[7] = {0.f, 0.f, 0.f, 0.f, 0.f, 0.f, 0.f};
        float wb[4] = {0.f, 0.f, 0.f, 0.f};
        if (u < 6) {
#pragma unroll
            for (int g4 = 0; g4 < 4; ++g4)
#pragma unroll
                for (int k = 0; k < 6; ++k)
                    pw[g4 * 12 + k] = whh3[(g4 * 6 + u) * 6 + k];
        } else if (u < 12) {
            const int q = u - 6;
#pragma unroll
            for (int g4 = 0; g4 < 4; ++g4) {
#pragma unroll
                for (int k = 0; k < 6; ++k) {
                    pw[g4 * 12 + k]     = wih4[(g4 * 6 + q) * 6 + k];
                    pw[g4 * 12 + 6 + k] = whh4[(g4 * 6 + q) * 6 + k];
                }
                wb[g4] = b4v[g4 * 6 + q];
            }
        } else if (u < 18) {
            const int q = u - 12;
#pragma unroll
            for (int k = 0; k < 6; ++k) wf[k] = fcw[q * 6 + k];
            wf[6] = fcb[q];
        }
        const float* prb = pr3 + (size_t)b * T_SZ * 24;
        float* outb = out + (size_t)b * T_SZ * 6;
        unsigned* fin = flags + 192 + b;
        const int up  = (u < 24) ? u : 23;
        const int bpa = ((u % 6) * 4);

        wait_flag(fin, (T_SZ < CHUNK + PF) ? T_SZ : (CHUNK + PF));
        float pf[4];
#pragma unroll
        for (int s = 0; s < 4; ++s) pf[s] = prb[(size_t)s * 24 + up];
        float hS = 0.0f, cS = 0.0f;

        for (int t4 = 0; t4 < T_SZ + 4; t4 += 4) {
            if (t4 && t4 < T_SZ && (t4 & (CHUNK - 1)) == 0) {
                unsigned need = t4 + CHUNK + PF;
                if (need > T_SZ) need = T_SZ;
                wait_flag(fin, need);
            }
#pragma unroll
            for (int s = 0; s < 4; ++s) {
                const int t = t4 + s;
                const int hb = __builtin_bit_cast(int, hS);
                float v[12];
#pragma unroll
                for (int k = 0; k < 12; ++k)
                    v[k] = as_f(__builtin_amdgcn_readlane(hb, k));
                // FC: out[t-2] from h4[t-2]
                if (t >= 2 && t < T_SZ + 2 && u >= 12 && u < 18) {
                    float o = wf[6];
#pragma unroll
                    for (int k = 0; k < 6; ++k) o = fmaf(wf[k], v[6 + k], o);
                    outb[(size_t)(t - 2) * 6 + (u - 12)] = o;
                }
                // gather proj[t] for L3 lanes (lanes 0-23 hold pr3[t][u])
                float pj[4];
                {
                    const int prbits = __builtin_bit_cast(int, pf[s]);
#pragma unroll
                    for (int g4 = 0; g4 < 4; ++g4)
                        pj[g4] = as_f(__builtin_amdgcn_ds_bpermute(bpa + g4 * 24, prbits));
                }
                // prefetch proj[t+4]
                {
                    const int tp = (t + 4 < T_SZ) ? (t + 4) : (T_SZ - 1);
                    pf[s] = prb[(size_t)tp * 24 + up];
                }
                // cells: lanes 0-5 L3 at t; lanes 6-11 L4 at t-1
                const bool is_l4 = (u >= 6 && u < 12);
                float pg[4];
#pragma unroll
                for (int g4 = 0; g4 < 4; ++g4) {
                    float a = is_l4 ? wb[g4] : pj[g4];
#pragma unroll
                    for (int k = 0; k < 12; ++k) a = fmaf(pw[g4 * 12 + k], v[k], a);
                    pg[g4] = a;
                }
                const bool act = (u < 6 && t < T_SZ) || (is_l4 && t >= 1 && t <= T_SZ);
                if (act) lstm_cell(pg[0], pg[1], pg[2], pg[3], cS, hS);
            }
        }
    }
}

extern "C" void kernel_launch(void* const* d_in, const int* in_sizes, int n_in,
                              void* d_out, int out_size, void* d_ws, size_t ws_size,
                              hipStream_t stream) {
    const float* x      = (const float*)d_in[0];
    const float* w1_ih0 = (const float*)d_in[1];
    const float* w1_hh0 = (const float*)d_in[2];
    const float* b1_0   = (const float*)d_in[3];
    const float* w1_ih1 = (const float*)d_in[4];
    const float* w1_hh1 = (const float*)d_in[5];
    const float* b1_1   = (const float*)d_in[6];
    const float* w2_ih0 = (const float*)d_in[7];
    const float* w2_hh0 = (const float*)d_in[8];
    const float* b2_0   = (const float*)d_in[9];
    const float* w2_ih1 = (const float*)d_in[10];
    const float* w2_hh1 = (const float*)d_in[11];
    const float* b2_1   = (const float*)d_in[12];
    const float* fc_w   = (const float*)d_in[13];
    const float* fc_b   = (const float*)d_in[14];
    float* out = (float*)d_out;

    const int M = M_SZ;
    float*    xg    = (float*)d_ws;                        // M*256 f32 (also pre2)
    unsigned* h1p   = (unsigned*)(xg + (size_t)M * 256);   // M*32  u32
    float*    h2g   = (float*)(h1p + (size_t)M * 32);      // M*64  f32
    float*    pr3   = h2g + (size_t)M * 64;                // M*24  f32
    _Float16* w16a  = (_Float16*)(pr3 + (size_t)M * 24);   // 256*512 f16
    unsigned* flags = (unsigned*)(w16a + 256 * 512);       // 256 u32

    init_flags<<<1, 256, 0, stream>>>(flags);
    f32_to_f16<<<(256 * 512 + 255) / 256, 256, 0, stream>>>(w1_ih0, w16a, 256 * 512);

    // L1 input projection (x known upfront): 512 -> 256 gates, bias folded
    gemm_mfma<512><<<M / 64, 256, 0, stream>>>(x, w16a, b1_0, xg);

    // all recurrent layers, balanced cross-block pipeline
    lstm_pipe<<<320, 256, 0, stream>>>(xg, xg, w1_hh0,
                                       w1_ih1, w1_hh1, b1_1,
                                       w2_ih0, w2_hh0, b2_0,
                                       w2_ih1, w2_hh1, b2_1,
                                       fc_w, fc_b,
                                       h1p, h2g, pr3, flags, out);
}